// Round 13
// baseline (317.449 us; speedup 1.0000x reference)
//
#include <hip/hip_runtime.h>
#include <hip/hip_bf16.h>
#include <math.h>

// ChebyNet: 2-layer ChebConv (K=4), N=100000, E=1600000, F 32->16->10, log_softmax.
//
// R13 = R12 with the compile fix: __builtin_nontemporal_load requires native
// clang vector types, not HIP_vector_type structs -> vec4i/vec4u typedefs
// (ext_vector_type(4), identical 16B layout).
// R12 content: (a) edge lists padded to x4 with sentinel src=N (row N of all
// gather tables zeroed) -> aligned int4 psrc loads, no divergent remainder;
// exact for pure gather-SUMS. (b) nontemporal loads/stores on read-once
// streams (psrc, tmp, prev tables) so L2 retains the gather tables.
// Rest = R11: U-space recurrence, bf16 tables (64B rows L1, 32B rows L2),
// fixed-capacity bucket CSR build, __launch_bounds__ everywhere.

#define BLK 256
#define BLKP 512
#define NBUCK_MAX 256   // buckets = ceil(N/512); requires N <= 131072
#define CHUNK 8192      // edges per binned_scatter block
#define CAPB 16384      // fixed capacity per bucket region in tmp/psrc
#define PLACE_CAP 10240 // LDS staging capacity in bucket_place (padded mean ~8960)

typedef int vec4i __attribute__((ext_vector_type(4)));
typedef unsigned int vec4u __attribute__((ext_vector_type(4)));

// ---------- bf16 helpers (storage-only quantization) ----------
__device__ inline unsigned short f32_to_bf16_rne(float f) {
    unsigned int u = __float_as_uint(f);
    unsigned int rounding = 0x7FFFu + ((u >> 16) & 1u);
    return (unsigned short)((u + rounding) >> 16);
}
__device__ inline unsigned int pack_bf16x2(float a, float b) {
    return (unsigned int)f32_to_bf16_rne(a) | ((unsigned int)f32_to_bf16_rne(b) << 16);
}
__device__ inline void unpack8v(const vec4u u, float* f) {
#pragma unroll
    for (int j = 0; j < 4; j++) {
        unsigned int w = u[j];
        f[2 * j]     = __uint_as_float(w << 16);
        f[2 * j + 1] = __uint_as_float(w & 0xFFFF0000u);
    }
}
__device__ inline void add8(const uint4 u, float* acc) {
    const unsigned int* p = &u.x;
#pragma unroll
    for (int j = 0; j < 4; j++) {
        unsigned int w = p[j];
        acc[2 * j]     += __uint_as_float(w << 16);
        acc[2 * j + 1] += __uint_as_float(w & 0xFFFF0000u);
    }
}
__device__ inline uint4 pack8(const float* r) {
    uint4 o;
    o.x = pack_bf16x2(r[0], r[1]);
    o.y = pack_bf16x2(r[2], r[3]);
    o.z = pack_bf16x2(r[4], r[5]);
    o.w = pack_bf16x2(r[6], r[7]);
    return o;
}

// FMA one bf16x8 chunk (scaled s) vs 8x16 slab, but only 8 output cols (stride 16)
__device__ inline void fma8_w8(const uint4 u, float s, const float* __restrict__ W,
                               float* acc) {
    const unsigned int* p = &u.x;
#pragma unroll
    for (int q = 0; q < 4; q++) {
        float fa = __uint_as_float(p[q] << 16) * s;
        float fb = __uint_as_float(p[q] & 0xFFFF0000u) * s;
        const float* Wa = W + (2 * q) * 16;
        const float* Wb = W + (2 * q + 1) * 16;
#pragma unroll
        for (int j = 0; j < 8; j++) acc[j] += fa * Wa[j] + fb * Wb[j];
    }
}
// FMA one bf16x8 chunk (scaled s) vs 8x10 slab into acc[10]
__device__ inline void fma8_w10(const uint4 u, float s, const float* __restrict__ W,
                                float* acc) {
    const unsigned int* p = &u.x;
#pragma unroll
    for (int q = 0; q < 4; q++) {
        float fa = __uint_as_float(p[q] << 16) * s;
        float fb = __uint_as_float(p[q] & 0xFFFF0000u) * s;
        const float* Wa = W + (2 * q) * 10;
        const float* Wb = W + (2 * q + 1) * 10;
#pragma unroll
        for (int j = 0; j < 10; j++) acc[j] += fa * Wa[j] + fb * Wb[j];
    }
}

// ---------- CSR build (fixed-capacity buckets) ----------
__global__ __launch_bounds__(BLK)
void binned_scatter_kernel(const int* __restrict__ src, const int* __restrict__ dst,
                           int* __restrict__ bfill, int* __restrict__ tmp,
                           int E, int nbuck) {
    __shared__ int cnt[NBUCK_MAX];
    __shared__ int lofs[NBUCK_MAX + 1];
    __shared__ int pos[NBUCK_MAX];
    __shared__ int gbase[NBUCK_MAX];
    __shared__ int stage[CHUNK];
    __shared__ unsigned char bkt[CHUNK];

    int tid = threadIdx.x;
    int e0 = blockIdx.x * CHUNK;
    int nE = min(CHUNK, E - e0);

    for (int b = tid; b < nbuck; b += BLK) { cnt[b] = 0; pos[b] = 0; }
    __syncthreads();

    for (int i = tid; i < nE; i += BLK) {
        int d = dst[e0 + i];
        atomicAdd(&cnt[d >> 9], 1);
    }
    __syncthreads();

    {
        int v = (tid < nbuck) ? cnt[tid] : 0;
        lofs[tid] = v;
        __syncthreads();
        for (int off = 1; off < BLK; off <<= 1) {
            int t = (tid >= off) ? lofs[tid - off] : 0;
            __syncthreads();
            lofs[tid] += t;
            __syncthreads();
        }
        int incl = lofs[tid];
        __syncthreads();
        lofs[tid] = incl - v;
        if (tid == 0) lofs[nbuck] = nE;
        if (tid < nbuck && v > 0)
            gbase[tid] = tid * CAPB + atomicAdd(&bfill[tid], v);
    }
    __syncthreads();

    for (int i = tid; i < nE; i += BLK) {
        int s = src[e0 + i];
        int d = dst[e0 + i];
        int b = d >> 9;
        int slot = lofs[b] + atomicAdd(&pos[b], 1);
        stage[slot] = (s << 9) | (d & 511);
        bkt[slot] = (unsigned char)b;
    }
    __syncthreads();

    for (int i = tid; i < nE; i += BLK) {
        int b = bkt[i];
        __builtin_nontemporal_store(stage[i], &tmp[gbase[b] + (i - lofs[b])]);
    }
}

// Phase 2: per-bucket LDS degree count/scan (PADDED to x4 per node) ->
// rowbeg/rowend/dis/d2/inv; rank+stage; sentinel-pad (src=N); coalesced flush.
__global__ __launch_bounds__(BLKP)
void bucket_place_kernel(const int* __restrict__ bfill, const int* __restrict__ tmp,
                         int* __restrict__ psrc, int* __restrict__ rowbeg,
                         int* __restrict__ rowend, float* __restrict__ dis,
                         float* __restrict__ d2, float* __restrict__ inv, int N) {
    __shared__ int cnt[512];
    __shared__ int ofs[512];
    __shared__ int fill[512];
    __shared__ int stage[PLACE_CAP];
    __shared__ int totpad_s;

    int b = blockIdx.x;
    int tid = threadIdx.x;
    int n0 = b << 9;
    int nn = min(512, N - n0);
    int S = b * CAPB;
    int tot = bfill[b];

    cnt[tid] = 0;
    fill[tid] = 0;
    __syncthreads();

    for (int i = tid; i < tot; i += BLKP) atomicAdd(&cnt[tmp[S + i] & 511], 1);
    __syncthreads();

    int v = cnt[tid];            // true degree
    int vp = (v + 3) & ~3;       // padded to multiple of 4
    ofs[tid] = vp;
    __syncthreads();
    for (int off = 1; off < 512; off <<= 1) {
        int t = (tid >= off) ? ofs[tid - off] : 0;
        __syncthreads();
        ofs[tid] += t;
        __syncthreads();
    }
    if (tid == 511) totpad_s = ofs[511];
    int excl = ofs[tid] - vp;    // padded exclusive
    __syncthreads();
    ofs[tid] = excl;
    if (tid < nn) {
        rowbeg[n0 + tid] = S + excl;
        rowend[n0 + tid] = S + excl + vp;   // includes sentinel pads (gather zeros)
        float fv = (float)v;
        dis[n0 + tid] = (v > 0) ? rsqrtf(fv) : 0.0f;
        d2[n0 + tid]  = (v > 0) ? 1.0f / fv : 0.0f;
        inv[n0 + tid] = (v > 0) ? sqrtf(fv) : 0.0f;
    }
    __syncthreads();
    int totpad = totpad_s;

    if (totpad <= PLACE_CAP) {
        for (int i = tid; i < tot; i += BLKP) {
            int rec = __builtin_nontemporal_load(&tmp[S + i]);
            int nl = rec & 511;
            int slot = ofs[nl] + atomicAdd(&fill[nl], 1);
            stage[slot] = rec >> 9;
        }
        // sentinel pads
        if (tid < nn) {
            int e = ofs[tid];
            for (int j = v; j < vp; j++) stage[e + j] = N;
        }
        __syncthreads();
        for (int i = tid; i < totpad; i += BLKP) psrc[S + i] = stage[i];
    } else {
        // statistically unreachable fallback: direct scatter (L2-hot window)
        for (int i = tid; i < tot; i += BLKP) {
            int rec = __builtin_nontemporal_load(&tmp[S + i]);
            int nl = rec & 511;
            int slot = S + ofs[nl] + atomicAdd(&fill[nl], 1);
            psrc[slot] = rec >> 9;
        }
        if (tid < nn) {
            int e = S + ofs[tid];
            for (int j = v; j < vp; j++) psrc[e + j] = N;
        }
    }
}

// U0[n] = dis[n]*x[n], bf16 64B rows; ALSO zeroes sentinel row N of all 8 tables.
__global__ __launch_bounds__(BLK)
void cvt_u0_kernel(const float* __restrict__ x, const float* __restrict__ dis,
                   uint4* __restrict__ u0, uint4* __restrict__ u1,
                   uint4* __restrict__ u2, uint4* __restrict__ u3,
                   uint4* __restrict__ uh, uint4* __restrict__ us1,
                   uint4* __restrict__ us2, uint4* __restrict__ us3, int N) {
    int t = blockIdx.x * blockDim.x + threadIdx.x;  // one 16B chunk (8 feats)
    if (t < N * 4) {
        int n = t >> 2;
        int c = t & 3;
        float dn = dis[n];
        const float4* in4 = reinterpret_cast<const float4*>(x + (size_t)n * 32 + c * 8);
        float4 a = in4[0], b = in4[1];
        float r[8] = {dn * a.x, dn * a.y, dn * a.z, dn * a.w,
                      dn * b.x, dn * b.y, dn * b.z, dn * b.w};
        u0[(size_t)n * 4 + c] = pack8(r);
        return;
    }
    int ex = t - N * 4;
    if (ex < 24) {  // zero sentinel row N: 4 big tables x4 chunks + 4 small x2
        uint4 z = make_uint4(0, 0, 0, 0);
        if (ex < 16) {
            uint4* tb[4] = {u0, u1, u2, u3};
            tb[ex >> 2][(size_t)N * 4 + (ex & 3)] = z;
        } else {
            uint4* tb[4] = {uh, us1, us2, us3};
            int e2 = ex - 16;
            tb[e2 >> 1][(size_t)N * 2 + (e2 & 1)] = z;
        }
    }
}

// ---------- U-space props: aligned int4 edge loads, pure gather-sum ----------
// epilogue: out = -scale*d2[n]*acc - prevU. C = chunks per row (4 or 2).
template <int C, bool HAVE_PREV>
__global__ __launch_bounds__(BLK)
void prop_u_kernel(const int* __restrict__ rowbeg, const int* __restrict__ rowend,
                   const int* __restrict__ psrc, const float* __restrict__ d2,
                   const uint4* __restrict__ vb, const uint4* __restrict__ prevb,
                   uint4* __restrict__ outb, float scale, int N) {
    int t = blockIdx.x * blockDim.x + threadIdx.x;
    int n = t / C;
    int c = t % C;
    if (n >= N) return;
    int beg = rowbeg[n];   // multiple of 4 by construction
    int end = rowend[n];   // multiple of 4 (sentinel-padded)
    float acc[8];
#pragma unroll
    for (int j = 0; j < 8; j++) acc[j] = 0.f;
    for (int i = beg; i < end; i += 4) {
        vec4i e = __builtin_nontemporal_load(reinterpret_cast<const vec4i*>(psrc + i));
        uint4 a0 = vb[(size_t)e.x * C + c];
        uint4 a1 = vb[(size_t)e.y * C + c];
        uint4 a2 = vb[(size_t)e.z * C + c];
        uint4 a3 = vb[(size_t)e.w * C + c];
        add8(a0, acc);
        add8(a1, acc);
        add8(a2, acc);
        add8(a3, acc);
    }
    float f = -scale * d2[n];
    float r[8];
    if (HAVE_PREV) {
        vec4u pv = __builtin_nontemporal_load(
            reinterpret_cast<const vec4u*>(prevb + (size_t)n * C + c));
        float p[8];
        unpack8v(pv, p);
#pragma unroll
        for (int j = 0; j < 8; j++) r[j] = f * acc[j] - p[j];
    } else {
#pragma unroll
        for (int j = 0; j < 8; j++) r[j] = f * acc[j];
    }
    outb[(size_t)n * C + c] = pack8(r);
}

// h = relu(b1 + x@W1[0] + sum_{k=1..3} (Uk*inv)@W1[k]); deg-0: Tx2=-x.
// 2 threads/node (outputs split 8+8) -> no spill.
__global__ __launch_bounds__(BLK)
void combine1_kernel(const float* __restrict__ x, const uint4* __restrict__ u1,
                     const uint4* __restrict__ u2, const uint4* __restrict__ u3,
                     const float* __restrict__ inv, const float* __restrict__ dis,
                     const float* __restrict__ W1, const float* __restrict__ b1,
                     uint4* __restrict__ hb, uint4* __restrict__ uh, int N) {
    __shared__ float sW[4 * 32 * 16];
    __shared__ float sb[16];
    for (int i = threadIdx.x; i < 4 * 32 * 16; i += blockDim.x) sW[i] = W1[i];
    if (threadIdx.x < 16) sb[threadIdx.x] = b1[threadIdx.x];
    __syncthreads();
    int t = blockIdx.x * blockDim.x + threadIdx.x;
    int n = t >> 1;
    int h = t & 1;          // output half
    if (n >= N) return;
    const float* sWh = sW + h * 8;   // column offset
    float acc[8];
#pragma unroll
    for (int j = 0; j < 8; j++) acc[j] = sb[h * 8 + j];
    {
        const float4* in4 = reinterpret_cast<const float4*>(x + (size_t)n * 32);
#pragma unroll
        for (int q = 0; q < 8; q++) {
            float4 a = in4[q];
            const float* Wq = sWh + q * 4 * 16;
#pragma unroll
            for (int j = 0; j < 8; j++)
                acc[j] += a.x * Wq[j] + a.y * Wq[16 + j] + a.z * Wq[32 + j] + a.w * Wq[48 + j];
        }
    }
    float iv = inv[n];
#pragma unroll
    for (int c = 0; c < 4; c++) fma8_w8(u1[(size_t)n * 4 + c], iv, sWh + 512 + c * 128, acc);
#pragma unroll
    for (int c = 0; c < 4; c++) fma8_w8(u2[(size_t)n * 4 + c], iv, sWh + 1024 + c * 128, acc);
#pragma unroll
    for (int c = 0; c < 4; c++) fma8_w8(u3[(size_t)n * 4 + c], iv, sWh + 1536 + c * 128, acc);
    if (iv == 0.0f) {  // deg-0 (rare): Tx2 = -x; Tx1 = Tx3 = 0 already
        const float4* in4 = reinterpret_cast<const float4*>(x + (size_t)n * 32);
#pragma unroll
        for (int q = 0; q < 8; q++) {
            float4 a = in4[q];
            const float* Wq = sWh + 1024 + q * 4 * 16;
#pragma unroll
            for (int j = 0; j < 8; j++)
                acc[j] -= a.x * Wq[j] + a.y * Wq[16 + j] + a.z * Wq[32 + j] + a.w * Wq[48 + j];
        }
    }
    float dn = dis[n];
    float r[8], u[8];
#pragma unroll
    for (int j = 0; j < 8; j++) {
        r[j] = fmaxf(acc[j], 0.0f);
        u[j] = dn * r[j];
    }
    hb[(size_t)n * 2 + h] = pack8(r);
    uh[(size_t)n * 2 + h] = pack8(u);
}

// o = log_softmax(b2 + h@W2[0] + sum_k (USk*inv)@W2[k]); deg-0: S2=-h.
__global__ __launch_bounds__(BLK)
void combine2_kernel(const uint4* __restrict__ hb, const uint4* __restrict__ us1,
                     const uint4* __restrict__ us2, const uint4* __restrict__ us3,
                     const float* __restrict__ inv,
                     const float* __restrict__ W2, const float* __restrict__ b2,
                     float* __restrict__ out, int N) {
    __shared__ float sW[4 * 16 * 10];
    __shared__ float sb[10];
    for (int i = threadIdx.x; i < 4 * 16 * 10; i += blockDim.x) sW[i] = W2[i];
    if (threadIdx.x < 10) sb[threadIdx.x] = b2[threadIdx.x];
    __syncthreads();
    int n = blockIdx.x * blockDim.x + threadIdx.x;
    if (n >= N) return;
    float acc[10];
#pragma unroll
    for (int c = 0; c < 10; c++) acc[c] = sb[c];
    float iv = inv[n];
#pragma unroll
    for (int c = 0; c < 2; c++) fma8_w10(hb[(size_t)n * 2 + c],  1.0f, sW + c * 80, acc);
#pragma unroll
    for (int c = 0; c < 2; c++) fma8_w10(us1[(size_t)n * 2 + c], iv, sW + 160 + c * 80, acc);
#pragma unroll
    for (int c = 0; c < 2; c++) fma8_w10(us2[(size_t)n * 2 + c], iv, sW + 320 + c * 80, acc);
#pragma unroll
    for (int c = 0; c < 2; c++) fma8_w10(us3[(size_t)n * 2 + c], iv, sW + 480 + c * 80, acc);
    if (iv == 0.0f) {  // deg-0 (rare): S2 = -h
#pragma unroll
        for (int c = 0; c < 2; c++) fma8_w10(hb[(size_t)n * 2 + c], -1.0f, sW + 320 + c * 80, acc);
    }
    float m = acc[0];
#pragma unroll
    for (int c = 1; c < 10; c++) m = fmaxf(m, acc[c]);
    float sum = 0.0f;
#pragma unroll
    for (int c = 0; c < 10; c++) sum += expf(acc[c] - m);
    float lse = m + logf(sum);
    float* o = out + (size_t)n * 10;
#pragma unroll
    for (int c = 0; c < 10; c++) o[c] = acc[c] - lse;
}

extern "C" void kernel_launch(void* const* d_in, const int* in_sizes, int n_in,
                              void* d_out, int out_size, void* d_ws, size_t ws_size,
                              hipStream_t stream) {
    const float* x  = (const float*)d_in[0];
    const int*   ei = (const int*)d_in[1];
    const float* W1 = (const float*)d_in[2];
    const float* b1 = (const float*)d_in[3];
    const float* W2 = (const float*)d_in[4];
    const float* b2 = (const float*)d_in[5];
    float* out = (float*)d_out;

    const int N = in_sizes[0] / 32;   // 100000
    const int E = in_sizes[1] / 2;    // 1600000
    const int* src = ei;
    const int* dst = ei + E;

    const int nbuck = (N + 511) / 512;        // 196

    // workspace layout (16B-aligned regions); tables have N+1 rows (sentinel)
    char* w = (char*)d_ws;
    int*   bfill  = (int*)w;              w += NBUCK_MAX * 4;
    int*   rowbeg = (int*)w;              w += (size_t)(N + 4) * 4;
    int*   rowend = (int*)w;              w += (size_t)(N + 4) * 4;
    float* dis    = (float*)w;            w += (size_t)N * 4;
    float* d2     = (float*)w;            w += (size_t)N * 4;
    float* inv    = (float*)w;            w += (size_t)(N + 4) * 4;
    int*   tmp    = (int*)w;              w += (size_t)NBUCK_MAX * CAPB * 4;
    int*   psrc   = (int*)w;              w += (size_t)NBUCK_MAX * CAPB * 4;
    uint4* u0     = (uint4*)w;            w += (size_t)64 * (N + 1);  // 64B rows
    uint4* u1     = (uint4*)w;            w += (size_t)64 * (N + 1);
    uint4* u2     = (uint4*)w;            w += (size_t)64 * (N + 1);
    uint4* u3     = (uint4*)w;            w += (size_t)64 * (N + 1);
    uint4* hb     = (uint4*)w;            w += (size_t)32 * (N + 1);  // 32B rows
    uint4* uh     = (uint4*)w;            w += (size_t)32 * (N + 1);
    uint4* us1    = (uint4*)w;            w += (size_t)32 * (N + 1);
    uint4* us2    = (uint4*)w;            w += (size_t)32 * (N + 1);
    uint4* us3    = (uint4*)w;            w += (size_t)32 * (N + 1);

    int gN   = (N + BLK - 1) / BLK;
    int gN2  = (N * 2 + BLK - 1) / BLK;        // combine1: 2 threads/node
    int gU32 = (N * 4 + BLK - 1) / BLK;        // 4 lanes/node
    int gU16 = (N * 2 + BLK - 1) / BLK;        // 2 lanes/node
    int gCVT = (N * 4 + 24 + BLK - 1) / BLK;   // +24 sentinel-zero threads
    int gCH  = (E + CHUNK - 1) / CHUNK;

    // ---- CSR build ----
    hipMemsetAsync(bfill, 0, NBUCK_MAX * sizeof(int), stream);
    binned_scatter_kernel<<<gCH, BLK, 0, stream>>>(src, dst, bfill, tmp, E, nbuck);
    bucket_place_kernel<<<nbuck, BLKP, 0, stream>>>(bfill, tmp, psrc, rowbeg, rowend,
                                                    dis, d2, inv, N);

    // ---- layer 1 (F=32, bf16 U-tables, 64B rows) ----
    cvt_u0_kernel<<<gCVT, BLK, 0, stream>>>(x, dis, u0, u1, u2, u3, uh, us1, us2, us3, N);
    prop_u_kernel<4, false><<<gU32, BLK, 0, stream>>>(rowbeg, rowend, psrc, d2, u0, nullptr, u1, 1.0f, N);
    prop_u_kernel<4, true ><<<gU32, BLK, 0, stream>>>(rowbeg, rowend, psrc, d2, u1, u0,      u2, 2.0f, N);
    prop_u_kernel<4, true ><<<gU32, BLK, 0, stream>>>(rowbeg, rowend, psrc, d2, u2, u1,      u3, 2.0f, N);
    combine1_kernel<<<gN2, BLK, 0, stream>>>(x, u1, u2, u3, inv, dis, W1, b1, hb, uh, N);

    // ---- layer 2 (F=16, bf16 U-tables, 32B rows) ----
    prop_u_kernel<2, false><<<gU16, BLK, 0, stream>>>(rowbeg, rowend, psrc, d2, uh,  nullptr, us1, 1.0f, N);
    prop_u_kernel<2, true ><<<gU16, BLK, 0, stream>>>(rowbeg, rowend, psrc, d2, us1, uh,      us2, 2.0f, N);
    prop_u_kernel<2, true ><<<gU16, BLK, 0, stream>>>(rowbeg, rowend, psrc, d2, us2, us1,     us3, 2.0f, N);
    combine2_kernel<<<gN, BLK, 0, stream>>>(hb, us1, us2, us3, inv, W2, b2, out, N);
}

// Round 14
// 284.957 us; speedup vs baseline: 1.1140x; 1.1140x over previous
//
#include <hip/hip_runtime.h>
#include <hip/hip_bf16.h>
#include <math.h>

// ChebyNet: 2-layer ChebConv (K=4), N=100000, E=1600000, F 32->16->10, log_softmax.
//
// R14: revert R12/R13 (padding = +9% gather traffic for an instruction-count
// win that didn't matter at VALUBusy~6%; nontemporal psrc defeated L2 reuse of
// the 6x-re-read edge stream -> 292->317 regression). Back to R11 structure +
// two targeted changes:
//   (a) prop inner loop widened 4->8 edges in flight (props are latency-bound:
//       deg~16 = ~4 dependent iterations; double the MLP per lane)
//   (b) cvt_u0 fused into bucket_place (which already computes dis and runs
//       at 196 blocks -- idle CUs absorb the conversion for free)
// Rest: U-space recurrence (props are pure gather-sums, U_k = dis*Tx_k,
// epilogue -scale*d2[n]*acc - prevU), bf16 tables (64B rows L1, 32B rows L2),
// fixed-capacity bucket CSR build, __launch_bounds__ everywhere.

#define BLK 256
#define BLKP 512
#define NBUCK_MAX 256   // buckets = ceil(N/512); requires N <= 131072
#define CHUNK 8192      // edges per binned_scatter block
#define CAPB 16384      // fixed capacity per bucket region in tmp/psrc
#define PLACE_CAP 10240 // LDS staging capacity in bucket_place (avg bucket 8192)

// ---------- bf16 helpers (storage-only quantization) ----------
__device__ inline unsigned short f32_to_bf16_rne(float f) {
    unsigned int u = __float_as_uint(f);
    unsigned int rounding = 0x7FFFu + ((u >> 16) & 1u);
    return (unsigned short)((u + rounding) >> 16);
}
__device__ inline unsigned int pack_bf16x2(float a, float b) {
    return (unsigned int)f32_to_bf16_rne(a) | ((unsigned int)f32_to_bf16_rne(b) << 16);
}
__device__ inline void unpack8(const uint4 u, float* f) {
    const unsigned int* p = &u.x;
#pragma unroll
    for (int j = 0; j < 4; j++) {
        unsigned int w = p[j];
        f[2 * j]     = __uint_as_float(w << 16);
        f[2 * j + 1] = __uint_as_float(w & 0xFFFF0000u);
    }
}
__device__ inline void add8(const uint4 u, float* acc) {
    const unsigned int* p = &u.x;
#pragma unroll
    for (int j = 0; j < 4; j++) {
        unsigned int w = p[j];
        acc[2 * j]     += __uint_as_float(w << 16);
        acc[2 * j + 1] += __uint_as_float(w & 0xFFFF0000u);
    }
}
__device__ inline uint4 pack8(const float* r) {
    uint4 o;
    o.x = pack_bf16x2(r[0], r[1]);
    o.y = pack_bf16x2(r[2], r[3]);
    o.z = pack_bf16x2(r[4], r[5]);
    o.w = pack_bf16x2(r[6], r[7]);
    return o;
}

// FMA one bf16x8 chunk (scaled s) vs 8x16 slab, but only 8 output cols (stride 16)
__device__ inline void fma8_w8(const uint4 u, float s, const float* __restrict__ W,
                               float* acc) {
    const unsigned int* p = &u.x;
#pragma unroll
    for (int q = 0; q < 4; q++) {
        float fa = __uint_as_float(p[q] << 16) * s;
        float fb = __uint_as_float(p[q] & 0xFFFF0000u) * s;
        const float* Wa = W + (2 * q) * 16;
        const float* Wb = W + (2 * q + 1) * 16;
#pragma unroll
        for (int j = 0; j < 8; j++) acc[j] += fa * Wa[j] + fb * Wb[j];
    }
}
// FMA one bf16x8 chunk (scaled s) vs 8x10 slab into acc[10]
__device__ inline void fma8_w10(const uint4 u, float s, const float* __restrict__ W,
                                float* acc) {
    const unsigned int* p = &u.x;
#pragma unroll
    for (int q = 0; q < 4; q++) {
        float fa = __uint_as_float(p[q] << 16) * s;
        float fb = __uint_as_float(p[q] & 0xFFFF0000u) * s;
        const float* Wa = W + (2 * q) * 10;
        const float* Wb = W + (2 * q + 1) * 10;
#pragma unroll
        for (int j = 0; j < 10; j++) acc[j] += fa * Wa[j] + fb * Wb[j];
    }
}

// ---------- CSR build (fixed-capacity buckets) ----------
__global__ __launch_bounds__(BLK)
void binned_scatter_kernel(const int* __restrict__ src, const int* __restrict__ dst,
                           int* __restrict__ bfill, int* __restrict__ tmp,
                           int E, int nbuck) {
    __shared__ int cnt[NBUCK_MAX];
    __shared__ int lofs[NBUCK_MAX + 1];
    __shared__ int pos[NBUCK_MAX];
    __shared__ int gbase[NBUCK_MAX];
    __shared__ int stage[CHUNK];
    __shared__ unsigned char bkt[CHUNK];

    int tid = threadIdx.x;
    int e0 = blockIdx.x * CHUNK;
    int nE = min(CHUNK, E - e0);

    for (int b = tid; b < nbuck; b += BLK) { cnt[b] = 0; pos[b] = 0; }
    __syncthreads();

    for (int i = tid; i < nE; i += BLK) {
        int d = dst[e0 + i];
        atomicAdd(&cnt[d >> 9], 1);
    }
    __syncthreads();

    {
        int v = (tid < nbuck) ? cnt[tid] : 0;
        lofs[tid] = v;
        __syncthreads();
        for (int off = 1; off < BLK; off <<= 1) {
            int t = (tid >= off) ? lofs[tid - off] : 0;
            __syncthreads();
            lofs[tid] += t;
            __syncthreads();
        }
        int incl = lofs[tid];
        __syncthreads();
        lofs[tid] = incl - v;
        if (tid == 0) lofs[nbuck] = nE;
        if (tid < nbuck && v > 0)
            gbase[tid] = tid * CAPB + atomicAdd(&bfill[tid], v);
    }
    __syncthreads();

    for (int i = tid; i < nE; i += BLK) {
        int s = src[e0 + i];
        int d = dst[e0 + i];
        int b = d >> 9;
        int slot = lofs[b] + atomicAdd(&pos[b], 1);
        stage[slot] = (s << 9) | (d & 511);
        bkt[slot] = (unsigned char)b;
    }
    __syncthreads();

    for (int i = tid; i < nE; i += BLK) {
        int b = bkt[i];
        tmp[gbase[b] + (i - lofs[b])] = stage[i];
    }
}

// Phase 2: per-bucket LDS degree count/scan -> rowbeg/rowend/dis/d2/inv,
// rank+stage+flush psrc; FUSED: u0[n] = dis[n]*x[n] (bf16 64B rows).
__global__ __launch_bounds__(BLKP)
void bucket_place_kernel(const int* __restrict__ bfill, const int* __restrict__ tmp,
                         int* __restrict__ psrc, int* __restrict__ rowbeg,
                         int* __restrict__ rowend, float* __restrict__ dis,
                         float* __restrict__ d2, float* __restrict__ inv,
                         const float* __restrict__ x, uint4* __restrict__ u0, int N) {
    __shared__ int cnt[512];
    __shared__ int ofs[512];
    __shared__ int fill[512];
    __shared__ int stage[PLACE_CAP];

    int b = blockIdx.x;
    int tid = threadIdx.x;
    int n0 = b << 9;
    int nn = min(512, N - n0);
    int S = b * CAPB;
    int tot = bfill[b];

    cnt[tid] = 0;
    fill[tid] = 0;
    __syncthreads();

    for (int i = tid; i < tot; i += BLKP) atomicAdd(&cnt[tmp[S + i] & 511], 1);
    __syncthreads();

    int v = cnt[tid];
    ofs[tid] = v;
    __syncthreads();
    for (int off = 1; off < 512; off <<= 1) {
        int t = (tid >= off) ? ofs[tid - off] : 0;
        __syncthreads();
        ofs[tid] += t;
        __syncthreads();
    }
    int excl = ofs[tid] - v;
    __syncthreads();
    ofs[tid] = excl;
    float dn = (v > 0) ? rsqrtf((float)v) : 0.0f;
    if (tid < nn) {
        int n = n0 + tid;
        rowbeg[n] = S + excl;
        rowend[n] = S + excl + v;
        float fv = (float)v;
        dis[n] = dn;
        d2[n]  = (v > 0) ? 1.0f / fv : 0.0f;
        inv[n] = (v > 0) ? sqrtf(fv) : 0.0f;
        // fused U0 conversion: u0[n] = dn * x[n] (bf16)
        const float4* xr = reinterpret_cast<const float4*>(x + (size_t)n * 32);
#pragma unroll
        for (int c = 0; c < 4; c++) {
            float4 a = xr[c * 2], bb = xr[c * 2 + 1];
            float r[8] = {dn * a.x, dn * a.y, dn * a.z, dn * a.w,
                          dn * bb.x, dn * bb.y, dn * bb.z, dn * bb.w};
            u0[(size_t)n * 4 + c] = pack8(r);
        }
    }
    __syncthreads();

    if (tot <= PLACE_CAP) {
        for (int i = tid; i < tot; i += BLKP) {
            int rec = tmp[S + i];
            int nl = rec & 511;
            int slot = ofs[nl] + atomicAdd(&fill[nl], 1);
            stage[slot] = rec >> 9;
        }
        __syncthreads();
        for (int i = tid; i < tot; i += BLKP) psrc[S + i] = stage[i];
    } else {
        // statistically unreachable fallback: direct scatter (L2-hot window)
        for (int i = tid; i < tot; i += BLKP) {
            int rec = tmp[S + i];
            int nl = rec & 511;
            int slot = S + ofs[nl] + atomicAdd(&fill[nl], 1);
            psrc[slot] = rec >> 9;
        }
    }
}

// ---------- U-space props: pure gather-sum, 8 edges in flight ----------
// epilogue: out = -scale*d2[n]*acc - prevU. C = chunks per row (4 or 2).
template <int C, bool HAVE_PREV>
__global__ __launch_bounds__(BLK)
void prop_u_kernel(const int* __restrict__ rowbeg, const int* __restrict__ rowend,
                   const int* __restrict__ psrc, const float* __restrict__ d2,
                   const uint4* __restrict__ vb, const uint4* __restrict__ prevb,
                   uint4* __restrict__ outb, float scale, int N) {
    int t = blockIdx.x * blockDim.x + threadIdx.x;
    int n = t / C;
    int c = t % C;
    if (n >= N) return;
    int beg = rowbeg[n];
    int end = rowend[n];
    float acc[8];
#pragma unroll
    for (int j = 0; j < 8; j++) acc[j] = 0.f;
    int i = beg;
    for (; i + 7 < end; i += 8) {
        int s0 = psrc[i],     s1 = psrc[i + 1], s2 = psrc[i + 2], s3 = psrc[i + 3];
        int s4 = psrc[i + 4], s5 = psrc[i + 5], s6 = psrc[i + 6], s7 = psrc[i + 7];
        uint4 a0 = vb[(size_t)s0 * C + c];
        uint4 a1 = vb[(size_t)s1 * C + c];
        uint4 a2 = vb[(size_t)s2 * C + c];
        uint4 a3 = vb[(size_t)s3 * C + c];
        uint4 a4 = vb[(size_t)s4 * C + c];
        uint4 a5 = vb[(size_t)s5 * C + c];
        uint4 a6 = vb[(size_t)s6 * C + c];
        uint4 a7 = vb[(size_t)s7 * C + c];
        add8(a0, acc); add8(a1, acc); add8(a2, acc); add8(a3, acc);
        add8(a4, acc); add8(a5, acc); add8(a6, acc); add8(a7, acc);
    }
    for (; i + 3 < end; i += 4) {
        int s0 = psrc[i], s1 = psrc[i + 1], s2 = psrc[i + 2], s3 = psrc[i + 3];
        uint4 a0 = vb[(size_t)s0 * C + c];
        uint4 a1 = vb[(size_t)s1 * C + c];
        uint4 a2 = vb[(size_t)s2 * C + c];
        uint4 a3 = vb[(size_t)s3 * C + c];
        add8(a0, acc); add8(a1, acc); add8(a2, acc); add8(a3, acc);
    }
    for (; i < end; i++) {
        uint4 a0 = vb[(size_t)psrc[i] * C + c];
        add8(a0, acc);
    }
    float f = -scale * d2[n];
    float r[8];
    if (HAVE_PREV) {
        float p[8];
        unpack8(prevb[(size_t)n * C + c], p);
#pragma unroll
        for (int j = 0; j < 8; j++) r[j] = f * acc[j] - p[j];
    } else {
#pragma unroll
        for (int j = 0; j < 8; j++) r[j] = f * acc[j];
    }
    outb[(size_t)n * C + c] = pack8(r);
}

// h = relu(b1 + x@W1[0] + sum_{k=1..3} (Uk*inv)@W1[k]); deg-0: Tx2=-x.
// 2 threads/node (outputs split 8+8) -> no spill.
__global__ __launch_bounds__(BLK)
void combine1_kernel(const float* __restrict__ x, const uint4* __restrict__ u1,
                     const uint4* __restrict__ u2, const uint4* __restrict__ u3,
                     const float* __restrict__ inv, const float* __restrict__ dis,
                     const float* __restrict__ W1, const float* __restrict__ b1,
                     uint4* __restrict__ hb, uint4* __restrict__ uh, int N) {
    __shared__ float sW[4 * 32 * 16];
    __shared__ float sb[16];
    for (int i = threadIdx.x; i < 4 * 32 * 16; i += blockDim.x) sW[i] = W1[i];
    if (threadIdx.x < 16) sb[threadIdx.x] = b1[threadIdx.x];
    __syncthreads();
    int t = blockIdx.x * blockDim.x + threadIdx.x;
    int n = t >> 1;
    int h = t & 1;          // output half
    if (n >= N) return;
    const float* sWh = sW + h * 8;   // column offset
    float acc[8];
#pragma unroll
    for (int j = 0; j < 8; j++) acc[j] = sb[h * 8 + j];
    {
        const float4* in4 = reinterpret_cast<const float4*>(x + (size_t)n * 32);
#pragma unroll
        for (int q = 0; q < 8; q++) {
            float4 a = in4[q];
            const float* Wq = sWh + q * 4 * 16;
#pragma unroll
            for (int j = 0; j < 8; j++)
                acc[j] += a.x * Wq[j] + a.y * Wq[16 + j] + a.z * Wq[32 + j] + a.w * Wq[48 + j];
        }
    }
    float iv = inv[n];
#pragma unroll
    for (int c = 0; c < 4; c++) fma8_w8(u1[(size_t)n * 4 + c], iv, sWh + 512 + c * 128, acc);
#pragma unroll
    for (int c = 0; c < 4; c++) fma8_w8(u2[(size_t)n * 4 + c], iv, sWh + 1024 + c * 128, acc);
#pragma unroll
    for (int c = 0; c < 4; c++) fma8_w8(u3[(size_t)n * 4 + c], iv, sWh + 1536 + c * 128, acc);
    if (iv == 0.0f) {  // deg-0 (rare): Tx2 = -x; Tx1 = Tx3 = 0 already
        const float4* in4 = reinterpret_cast<const float4*>(x + (size_t)n * 32);
#pragma unroll
        for (int q = 0; q < 8; q++) {
            float4 a = in4[q];
            const float* Wq = sWh + 1024 + q * 4 * 16;
#pragma unroll
            for (int j = 0; j < 8; j++)
                acc[j] -= a.x * Wq[j] + a.y * Wq[16 + j] + a.z * Wq[32 + j] + a.w * Wq[48 + j];
        }
    }
    float dn = dis[n];
    float r[8], u[8];
#pragma unroll
    for (int j = 0; j < 8; j++) {
        r[j] = fmaxf(acc[j], 0.0f);
        u[j] = dn * r[j];
    }
    hb[(size_t)n * 2 + h] = pack8(r);
    uh[(size_t)n * 2 + h] = pack8(u);
}

// o = log_softmax(b2 + h@W2[0] + sum_k (USk*inv)@W2[k]); deg-0: S2=-h.
__global__ __launch_bounds__(BLK)
void combine2_kernel(const uint4* __restrict__ hb, const uint4* __restrict__ us1,
                     const uint4* __restrict__ us2, const uint4* __restrict__ us3,
                     const float* __restrict__ inv,
                     const float* __restrict__ W2, const float* __restrict__ b2,
                     float* __restrict__ out, int N) {
    __shared__ float sW[4 * 16 * 10];
    __shared__ float sb[10];
    for (int i = threadIdx.x; i < 4 * 16 * 10; i += blockDim.x) sW[i] = W2[i];
    if (threadIdx.x < 10) sb[threadIdx.x] = b2[threadIdx.x];
    __syncthreads();
    int n = blockIdx.x * blockDim.x + threadIdx.x;
    if (n >= N) return;
    float acc[10];
#pragma unroll
    for (int c = 0; c < 10; c++) acc[c] = sb[c];
    float iv = inv[n];
#pragma unroll
    for (int c = 0; c < 2; c++) fma8_w10(hb[(size_t)n * 2 + c],  1.0f, sW + c * 80, acc);
#pragma unroll
    for (int c = 0; c < 2; c++) fma8_w10(us1[(size_t)n * 2 + c], iv, sW + 160 + c * 80, acc);
#pragma unroll
    for (int c = 0; c < 2; c++) fma8_w10(us2[(size_t)n * 2 + c], iv, sW + 320 + c * 80, acc);
#pragma unroll
    for (int c = 0; c < 2; c++) fma8_w10(us3[(size_t)n * 2 + c], iv, sW + 480 + c * 80, acc);
    if (iv == 0.0f) {  // deg-0 (rare): S2 = -h
#pragma unroll
        for (int c = 0; c < 2; c++) fma8_w10(hb[(size_t)n * 2 + c], -1.0f, sW + 320 + c * 80, acc);
    }
    float m = acc[0];
#pragma unroll
    for (int c = 1; c < 10; c++) m = fmaxf(m, acc[c]);
    float sum = 0.0f;
#pragma unroll
    for (int c = 0; c < 10; c++) sum += expf(acc[c] - m);
    float lse = m + logf(sum);
    float* o = out + (size_t)n * 10;
#pragma unroll
    for (int c = 0; c < 10; c++) o[c] = acc[c] - lse;
}

extern "C" void kernel_launch(void* const* d_in, const int* in_sizes, int n_in,
                              void* d_out, int out_size, void* d_ws, size_t ws_size,
                              hipStream_t stream) {
    const float* x  = (const float*)d_in[0];
    const int*   ei = (const int*)d_in[1];
    const float* W1 = (const float*)d_in[2];
    const float* b1 = (const float*)d_in[3];
    const float* W2 = (const float*)d_in[4];
    const float* b2 = (const float*)d_in[5];
    float* out = (float*)d_out;

    const int N = in_sizes[0] / 32;   // 100000
    const int E = in_sizes[1] / 2;    // 1600000
    const int* src = ei;
    const int* dst = ei + E;

    const int nbuck = (N + 511) / 512;        // 196

    // workspace layout (16B-aligned regions)
    char* w = (char*)d_ws;
    int*   bfill  = (int*)w;              w += NBUCK_MAX * 4;
    int*   rowbeg = (int*)w;              w += (size_t)(N + 4) * 4;
    int*   rowend = (int*)w;              w += (size_t)(N + 4) * 4;
    float* dis    = (float*)w;            w += (size_t)N * 4;
    float* d2     = (float*)w;            w += (size_t)N * 4;
    float* inv    = (float*)w;            w += (size_t)N * 4;
    int*   tmp    = (int*)w;              w += (size_t)NBUCK_MAX * CAPB * 4;
    int*   psrc   = (int*)w;              w += (size_t)NBUCK_MAX * CAPB * 4;
    uint4* u0     = (uint4*)w;            w += (size_t)64 * N;   // 32 bf16 = 64B rows
    uint4* u1     = (uint4*)w;            w += (size_t)64 * N;
    uint4* u2     = (uint4*)w;            w += (size_t)64 * N;
    uint4* u3     = (uint4*)w;            w += (size_t)64 * N;
    uint4* hb     = (uint4*)w;            w += (size_t)32 * N;   // 16 bf16 = 32B rows
    uint4* uh     = (uint4*)w;            w += (size_t)32 * N;
    uint4* us1    = (uint4*)w;            w += (size_t)32 * N;
    uint4* us2    = (uint4*)w;            w += (size_t)32 * N;
    uint4* us3    = (uint4*)w;            w += (size_t)32 * N;

    int gN   = (N + BLK - 1) / BLK;
    int gN2  = (N * 2 + BLK - 1) / BLK;   // combine1: 2 threads/node
    int gU32 = (N * 4 + BLK - 1) / BLK;   // 4 lanes/node
    int gU16 = (N * 2 + BLK - 1) / BLK;   // 2 lanes/node
    int gCH  = (E + CHUNK - 1) / CHUNK;

    // ---- CSR build (2 kernels; u0 conversion fused into bucket_place) ----
    hipMemsetAsync(bfill, 0, NBUCK_MAX * sizeof(int), stream);
    binned_scatter_kernel<<<gCH, BLK, 0, stream>>>(src, dst, bfill, tmp, E, nbuck);
    bucket_place_kernel<<<nbuck, BLKP, 0, stream>>>(bfill, tmp, psrc, rowbeg, rowend,
                                                    dis, d2, inv, x, u0, N);

    // ---- layer 1 (F=32, bf16 U-tables, 64B rows) ----
    prop_u_kernel<4, false><<<gU32, BLK, 0, stream>>>(rowbeg, rowend, psrc, d2, u0, nullptr, u1, 1.0f, N);
    prop_u_kernel<4, true ><<<gU32, BLK, 0, stream>>>(rowbeg, rowend, psrc, d2, u1, u0,      u2, 2.0f, N);
    prop_u_kernel<4, true ><<<gU32, BLK, 0, stream>>>(rowbeg, rowend, psrc, d2, u2, u1,      u3, 2.0f, N);
    combine1_kernel<<<gN2, BLK, 0, stream>>>(x, u1, u2, u3, inv, dis, W1, b1, hb, uh, N);

    // ---- layer 2 (F=16, bf16 U-tables, 32B rows) ----
    prop_u_kernel<2, false><<<gU16, BLK, 0, stream>>>(rowbeg, rowend, psrc, d2, uh,  nullptr, us1, 1.0f, N);
    prop_u_kernel<2, true ><<<gU16, BLK, 0, stream>>>(rowbeg, rowend, psrc, d2, us1, uh,      us2, 2.0f, N);
    prop_u_kernel<2, true ><<<gU16, BLK, 0, stream>>>(rowbeg, rowend, psrc, d2, us2, us1,     us3, 2.0f, N);
    combine2_kernel<<<gN, BLK, 0, stream>>>(hb, us1, us2, us3, inv, W2, b2, out, N);
}

// Round 15
// 280.160 us; speedup vs baseline: 1.1331x; 1.0171x over previous
//
#include <hip/hip_runtime.h>
#include <hip/hip_bf16.h>
#include <math.h>

// ChebyNet: 2-layer ChebConv (K=4), N=100000, E=1600000, F 32->16->10, log_softmax.
//
// R15 = R14 + src-QUARTILE-ordered edge lists (build-side only; prop untouched).
// Theory: prop<4>'s 6.4MB gather table exceeds the 4MB/XCD L2 -> line touches
// miss. With each node's edges ordered by src quartile and all prop blocks
// co-resident (6252 waves < 8192 capacity), threads sweep the table low->high
// in phase: instantaneous working set ~1.6MB << L2 -> touches become hits.
// (R7's feature-split doubled line touches; a src-range split doesn't -- each
// edge belongs to exactly one range.)
// Rest = R14: U-space recurrence (props = pure gather-sums, 8 edges in flight),
// bf16 tables (64B rows L1, 32B rows L2), fixed-capacity bucket CSR build,
// u0 conversion fused into bucket_place, __launch_bounds__ everywhere.

#define BLK 256
#define BLKP 512
#define NBUCK_MAX 256   // buckets = ceil(N/512); requires N <= 131072
#define CHUNK 8192      // edges per binned_scatter block
#define CAPB 16384      // fixed capacity per bucket region in tmp/psrc
#define PLACE_CAP 10240 // LDS staging capacity in bucket_place (avg bucket 8192)

// ---------- bf16 helpers (storage-only quantization) ----------
__device__ inline unsigned short f32_to_bf16_rne(float f) {
    unsigned int u = __float_as_uint(f);
    unsigned int rounding = 0x7FFFu + ((u >> 16) & 1u);
    return (unsigned short)((u + rounding) >> 16);
}
__device__ inline unsigned int pack_bf16x2(float a, float b) {
    return (unsigned int)f32_to_bf16_rne(a) | ((unsigned int)f32_to_bf16_rne(b) << 16);
}
__device__ inline void unpack8(const uint4 u, float* f) {
    const unsigned int* p = &u.x;
#pragma unroll
    for (int j = 0; j < 4; j++) {
        unsigned int w = p[j];
        f[2 * j]     = __uint_as_float(w << 16);
        f[2 * j + 1] = __uint_as_float(w & 0xFFFF0000u);
    }
}
__device__ inline void add8(const uint4 u, float* acc) {
    const unsigned int* p = &u.x;
#pragma unroll
    for (int j = 0; j < 4; j++) {
        unsigned int w = p[j];
        acc[2 * j]     += __uint_as_float(w << 16);
        acc[2 * j + 1] += __uint_as_float(w & 0xFFFF0000u);
    }
}
__device__ inline uint4 pack8(const float* r) {
    uint4 o;
    o.x = pack_bf16x2(r[0], r[1]);
    o.y = pack_bf16x2(r[2], r[3]);
    o.z = pack_bf16x2(r[4], r[5]);
    o.w = pack_bf16x2(r[6], r[7]);
    return o;
}

// FMA one bf16x8 chunk (scaled s) vs 8x16 slab, but only 8 output cols (stride 16)
__device__ inline void fma8_w8(const uint4 u, float s, const float* __restrict__ W,
                               float* acc) {
    const unsigned int* p = &u.x;
#pragma unroll
    for (int q = 0; q < 4; q++) {
        float fa = __uint_as_float(p[q] << 16) * s;
        float fb = __uint_as_float(p[q] & 0xFFFF0000u) * s;
        const float* Wa = W + (2 * q) * 16;
        const float* Wb = W + (2 * q + 1) * 16;
#pragma unroll
        for (int j = 0; j < 8; j++) acc[j] += fa * Wa[j] + fb * Wb[j];
    }
}
// FMA one bf16x8 chunk (scaled s) vs 8x10 slab into acc[10]
__device__ inline void fma8_w10(const uint4 u, float s, const float* __restrict__ W,
                                float* acc) {
    const unsigned int* p = &u.x;
#pragma unroll
    for (int q = 0; q < 4; q++) {
        float fa = __uint_as_float(p[q] << 16) * s;
        float fb = __uint_as_float(p[q] & 0xFFFF0000u) * s;
        const float* Wa = W + (2 * q) * 10;
        const float* Wb = W + (2 * q + 1) * 10;
#pragma unroll
        for (int j = 0; j < 10; j++) acc[j] += fa * Wa[j] + fb * Wb[j];
    }
}

// ---------- CSR build (fixed-capacity buckets) ----------
__global__ __launch_bounds__(BLK)
void binned_scatter_kernel(const int* __restrict__ src, const int* __restrict__ dst,
                           int* __restrict__ bfill, int* __restrict__ tmp,
                           int E, int nbuck) {
    __shared__ int cnt[NBUCK_MAX];
    __shared__ int lofs[NBUCK_MAX + 1];
    __shared__ int pos[NBUCK_MAX];
    __shared__ int gbase[NBUCK_MAX];
    __shared__ int stage[CHUNK];
    __shared__ unsigned char bkt[CHUNK];

    int tid = threadIdx.x;
    int e0 = blockIdx.x * CHUNK;
    int nE = min(CHUNK, E - e0);

    for (int b = tid; b < nbuck; b += BLK) { cnt[b] = 0; pos[b] = 0; }
    __syncthreads();

    for (int i = tid; i < nE; i += BLK) {
        int d = dst[e0 + i];
        atomicAdd(&cnt[d >> 9], 1);
    }
    __syncthreads();

    {
        int v = (tid < nbuck) ? cnt[tid] : 0;
        lofs[tid] = v;
        __syncthreads();
        for (int off = 1; off < BLK; off <<= 1) {
            int t = (tid >= off) ? lofs[tid - off] : 0;
            __syncthreads();
            lofs[tid] += t;
            __syncthreads();
        }
        int incl = lofs[tid];
        __syncthreads();
        lofs[tid] = incl - v;
        if (tid == 0) lofs[nbuck] = nE;
        if (tid < nbuck && v > 0)
            gbase[tid] = tid * CAPB + atomicAdd(&bfill[tid], v);
    }
    __syncthreads();

    for (int i = tid; i < nE; i += BLK) {
        int s = src[e0 + i];
        int d = dst[e0 + i];
        int b = d >> 9;
        int slot = lofs[b] + atomicAdd(&pos[b], 1);
        stage[slot] = (s << 9) | (d & 511);
        bkt[slot] = (unsigned char)b;
    }
    __syncthreads();

    for (int i = tid; i < nE; i += BLK) {
        int b = bkt[i];
        tmp[gbase[b] + (i - lofs[b])] = stage[i];
    }
}

// Phase 2: per-bucket degree count/scan -> rowbeg/rowend/dis/d2/inv + fused u0;
// rank+stage+flush psrc with each node's edges ORDERED BY SRC QUARTILE
// (phase-coherent table sweep in the props).
__global__ __launch_bounds__(BLKP)
void bucket_place_kernel(const int* __restrict__ bfill, const int* __restrict__ tmp,
                         int* __restrict__ psrc, int* __restrict__ rowbeg,
                         int* __restrict__ rowend, float* __restrict__ dis,
                         float* __restrict__ d2, float* __restrict__ inv,
                         const float* __restrict__ x, uint4* __restrict__ u0, int N) {
    __shared__ int cnt4[512 * 4];   // counts -> per-node quartile bases (in place)
    __shared__ int ofs[512];
    __shared__ int fill4[512 * 4];
    __shared__ int stage[PLACE_CAP];

    int b = blockIdx.x;
    int tid = threadIdx.x;
    int n0 = b << 9;
    int nn = min(512, N - n0);
    int S = b * CAPB;
    int tot = bfill[b];

    int t1 = N >> 2, t2 = N >> 1, t3 = t2 + t1;   // quartile thresholds

    for (int i = tid; i < 512 * 4; i += BLKP) { cnt4[i] = 0; fill4[i] = 0; }
    __syncthreads();

    for (int i = tid; i < tot; i += BLKP) {
        int rec = tmp[S + i];
        int nl = rec & 511;
        int s = rec >> 9;
        int q = (s >= t2) ? ((s >= t3) ? 3 : 2) : ((s >= t1) ? 1 : 0);
        atomicAdd(&cnt4[nl * 4 + q], 1);
    }
    __syncthreads();

    // per-node quartile bases (in place) + total degree
    int c0 = cnt4[tid * 4 + 0], c1 = cnt4[tid * 4 + 1];
    int c2 = cnt4[tid * 4 + 2], c3 = cnt4[tid * 4 + 3];
    int v = c0 + c1 + c2 + c3;
    cnt4[tid * 4 + 0] = 0;
    cnt4[tid * 4 + 1] = c0;
    cnt4[tid * 4 + 2] = c0 + c1;
    cnt4[tid * 4 + 3] = c0 + c1 + c2;
    ofs[tid] = v;
    __syncthreads();
    for (int off = 1; off < 512; off <<= 1) {
        int t = (tid >= off) ? ofs[tid - off] : 0;
        __syncthreads();
        ofs[tid] += t;
        __syncthreads();
    }
    int excl = ofs[tid] - v;
    __syncthreads();
    ofs[tid] = excl;
    float dn = (v > 0) ? rsqrtf((float)v) : 0.0f;
    if (tid < nn) {
        int n = n0 + tid;
        rowbeg[n] = S + excl;
        rowend[n] = S + excl + v;
        float fv = (float)v;
        dis[n] = dn;
        d2[n]  = (v > 0) ? 1.0f / fv : 0.0f;
        inv[n] = (v > 0) ? sqrtf(fv) : 0.0f;
        // fused U0 conversion: u0[n] = dn * x[n] (bf16)
        const float4* xr = reinterpret_cast<const float4*>(x + (size_t)n * 32);
#pragma unroll
        for (int c = 0; c < 4; c++) {
            float4 a = xr[c * 2], bb = xr[c * 2 + 1];
            float r[8] = {dn * a.x, dn * a.y, dn * a.z, dn * a.w,
                          dn * bb.x, dn * bb.y, dn * bb.z, dn * bb.w};
            u0[(size_t)n * 4 + c] = pack8(r);
        }
    }
    __syncthreads();

    if (tot <= PLACE_CAP) {
        for (int i = tid; i < tot; i += BLKP) {
            int rec = tmp[S + i];
            int nl = rec & 511;
            int s = rec >> 9;
            int q = (s >= t2) ? ((s >= t3) ? 3 : 2) : ((s >= t1) ? 1 : 0);
            int slot = ofs[nl] + cnt4[nl * 4 + q] + atomicAdd(&fill4[nl * 4 + q], 1);
            stage[slot] = s;
        }
        __syncthreads();
        for (int i = tid; i < tot; i += BLKP) psrc[S + i] = stage[i];
    } else {
        // statistically unreachable fallback: direct scatter (L2-hot window)
        for (int i = tid; i < tot; i += BLKP) {
            int rec = tmp[S + i];
            int nl = rec & 511;
            int s = rec >> 9;
            int q = (s >= t2) ? ((s >= t3) ? 3 : 2) : ((s >= t1) ? 1 : 0);
            int slot = S + ofs[nl] + cnt4[nl * 4 + q] + atomicAdd(&fill4[nl * 4 + q], 1);
            psrc[slot] = s;
        }
    }
}

// ---------- U-space props: pure gather-sum, 8 edges in flight ----------
// epilogue: out = -scale*d2[n]*acc - prevU. C = chunks per row (4 or 2).
template <int C, bool HAVE_PREV>
__global__ __launch_bounds__(BLK)
void prop_u_kernel(const int* __restrict__ rowbeg, const int* __restrict__ rowend,
                   const int* __restrict__ psrc, const float* __restrict__ d2,
                   const uint4* __restrict__ vb, const uint4* __restrict__ prevb,
                   uint4* __restrict__ outb, float scale, int N) {
    int t = blockIdx.x * blockDim.x + threadIdx.x;
    int n = t / C;
    int c = t % C;
    if (n >= N) return;
    int beg = rowbeg[n];
    int end = rowend[n];
    float acc[8];
#pragma unroll
    for (int j = 0; j < 8; j++) acc[j] = 0.f;
    int i = beg;
    for (; i + 7 < end; i += 8) {
        int s0 = psrc[i],     s1 = psrc[i + 1], s2 = psrc[i + 2], s3 = psrc[i + 3];
        int s4 = psrc[i + 4], s5 = psrc[i + 5], s6 = psrc[i + 6], s7 = psrc[i + 7];
        uint4 a0 = vb[(size_t)s0 * C + c];
        uint4 a1 = vb[(size_t)s1 * C + c];
        uint4 a2 = vb[(size_t)s2 * C + c];
        uint4 a3 = vb[(size_t)s3 * C + c];
        uint4 a4 = vb[(size_t)s4 * C + c];
        uint4 a5 = vb[(size_t)s5 * C + c];
        uint4 a6 = vb[(size_t)s6 * C + c];
        uint4 a7 = vb[(size_t)s7 * C + c];
        add8(a0, acc); add8(a1, acc); add8(a2, acc); add8(a3, acc);
        add8(a4, acc); add8(a5, acc); add8(a6, acc); add8(a7, acc);
    }
    for (; i + 3 < end; i += 4) {
        int s0 = psrc[i], s1 = psrc[i + 1], s2 = psrc[i + 2], s3 = psrc[i + 3];
        uint4 a0 = vb[(size_t)s0 * C + c];
        uint4 a1 = vb[(size_t)s1 * C + c];
        uint4 a2 = vb[(size_t)s2 * C + c];
        uint4 a3 = vb[(size_t)s3 * C + c];
        add8(a0, acc); add8(a1, acc); add8(a2, acc); add8(a3, acc);
    }
    for (; i < end; i++) {
        uint4 a0 = vb[(size_t)psrc[i] * C + c];
        add8(a0, acc);
    }
    float f = -scale * d2[n];
    float r[8];
    if (HAVE_PREV) {
        float p[8];
        unpack8(prevb[(size_t)n * C + c], p);
#pragma unroll
        for (int j = 0; j < 8; j++) r[j] = f * acc[j] - p[j];
    } else {
#pragma unroll
        for (int j = 0; j < 8; j++) r[j] = f * acc[j];
    }
    outb[(size_t)n * C + c] = pack8(r);
}

// h = relu(b1 + x@W1[0] + sum_{k=1..3} (Uk*inv)@W1[k]); deg-0: Tx2=-x.
// 2 threads/node (outputs split 8+8) -> no spill.
__global__ __launch_bounds__(BLK)
void combine1_kernel(const float* __restrict__ x, const uint4* __restrict__ u1,
                     const uint4* __restrict__ u2, const uint4* __restrict__ u3,
                     const float* __restrict__ inv, const float* __restrict__ dis,
                     const float* __restrict__ W1, const float* __restrict__ b1,
                     uint4* __restrict__ hb, uint4* __restrict__ uh, int N) {
    __shared__ float sW[4 * 32 * 16];
    __shared__ float sb[16];
    for (int i = threadIdx.x; i < 4 * 32 * 16; i += blockDim.x) sW[i] = W1[i];
    if (threadIdx.x < 16) sb[threadIdx.x] = b1[threadIdx.x];
    __syncthreads();
    int t = blockIdx.x * blockDim.x + threadIdx.x;
    int n = t >> 1;
    int h = t & 1;          // output half
    if (n >= N) return;
    const float* sWh = sW + h * 8;   // column offset
    float acc[8];
#pragma unroll
    for (int j = 0; j < 8; j++) acc[j] = sb[h * 8 + j];
    {
        const float4* in4 = reinterpret_cast<const float4*>(x + (size_t)n * 32);
#pragma unroll
        for (int q = 0; q < 8; q++) {
            float4 a = in4[q];
            const float* Wq = sWh + q * 4 * 16;
#pragma unroll
            for (int j = 0; j < 8; j++)
                acc[j] += a.x * Wq[j] + a.y * Wq[16 + j] + a.z * Wq[32 + j] + a.w * Wq[48 + j];
        }
    }
    float iv = inv[n];
#pragma unroll
    for (int c = 0; c < 4; c++) fma8_w8(u1[(size_t)n * 4 + c], iv, sWh + 512 + c * 128, acc);
#pragma unroll
    for (int c = 0; c < 4; c++) fma8_w8(u2[(size_t)n * 4 + c], iv, sWh + 1024 + c * 128, acc);
#pragma unroll
    for (int c = 0; c < 4; c++) fma8_w8(u3[(size_t)n * 4 + c], iv, sWh + 1536 + c * 128, acc);
    if (iv == 0.0f) {  // deg-0 (rare): Tx2 = -x; Tx1 = Tx3 = 0 already
        const float4* in4 = reinterpret_cast<const float4*>(x + (size_t)n * 32);
#pragma unroll
        for (int q = 0; q < 8; q++) {
            float4 a = in4[q];
            const float* Wq = sWh + 1024 + q * 4 * 16;
#pragma unroll
            for (int j = 0; j < 8; j++)
                acc[j] -= a.x * Wq[j] + a.y * Wq[16 + j] + a.z * Wq[32 + j] + a.w * Wq[48 + j];
        }
    }
    float dn = dis[n];
    float r[8], u[8];
#pragma unroll
    for (int j = 0; j < 8; j++) {
        r[j] = fmaxf(acc[j], 0.0f);
        u[j] = dn * r[j];
    }
    hb[(size_t)n * 2 + h] = pack8(r);
    uh[(size_t)n * 2 + h] = pack8(u);
}

// o = log_softmax(b2 + h@W2[0] + sum_k (USk*inv)@W2[k]); deg-0: S2=-h.
__global__ __launch_bounds__(BLK)
void combine2_kernel(const uint4* __restrict__ hb, const uint4* __restrict__ us1,
                     const uint4* __restrict__ us2, const uint4* __restrict__ us3,
                     const float* __restrict__ inv,
                     const float* __restrict__ W2, const float* __restrict__ b2,
                     float* __restrict__ out, int N) {
    __shared__ float sW[4 * 16 * 10];
    __shared__ float sb[10];
    for (int i = threadIdx.x; i < 4 * 16 * 10; i += blockDim.x) sW[i] = W2[i];
    if (threadIdx.x < 10) sb[threadIdx.x] = b2[threadIdx.x];
    __syncthreads();
    int n = blockIdx.x * blockDim.x + threadIdx.x;
    if (n >= N) return;
    float acc[10];
#pragma unroll
    for (int c = 0; c < 10; c++) acc[c] = sb[c];
    float iv = inv[n];
#pragma unroll
    for (int c = 0; c < 2; c++) fma8_w10(hb[(size_t)n * 2 + c],  1.0f, sW + c * 80, acc);
#pragma unroll
    for (int c = 0; c < 2; c++) fma8_w10(us1[(size_t)n * 2 + c], iv, sW + 160 + c * 80, acc);
#pragma unroll
    for (int c = 0; c < 2; c++) fma8_w10(us2[(size_t)n * 2 + c], iv, sW + 320 + c * 80, acc);
#pragma unroll
    for (int c = 0; c < 2; c++) fma8_w10(us3[(size_t)n * 2 + c], iv, sW + 480 + c * 80, acc);
    if (iv == 0.0f) {  // deg-0 (rare): S2 = -h
#pragma unroll
        for (int c = 0; c < 2; c++) fma8_w10(hb[(size_t)n * 2 + c], -1.0f, sW + 320 + c * 80, acc);
    }
    float m = acc[0];
#pragma unroll
    for (int c = 1; c < 10; c++) m = fmaxf(m, acc[c]);
    float sum = 0.0f;
#pragma unroll
    for (int c = 0; c < 10; c++) sum += expf(acc[c] - m);
    float lse = m + logf(sum);
    float* o = out + (size_t)n * 10;
#pragma unroll
    for (int c = 0; c < 10; c++) o[c] = acc[c] - lse;
}

extern "C" void kernel_launch(void* const* d_in, const int* in_sizes, int n_in,
                              void* d_out, int out_size, void* d_ws, size_t ws_size,
                              hipStream_t stream) {
    const float* x  = (const float*)d_in[0];
    const int*   ei = (const int*)d_in[1];
    const float* W1 = (const float*)d_in[2];
    const float* b1 = (const float*)d_in[3];
    const float* W2 = (const float*)d_in[4];
    const float* b2 = (const float*)d_in[5];
    float* out = (float*)d_out;

    const int N = in_sizes[0] / 32;   // 100000
    const int E = in_sizes[1] / 2;    // 1600000
    const int* src = ei;
    const int* dst = ei + E;

    const int nbuck = (N + 511) / 512;        // 196

    // workspace layout (16B-aligned regions)
    char* w = (char*)d_ws;
    int*   bfill  = (int*)w;              w += NBUCK_MAX * 4;
    int*   rowbeg = (int*)w;              w += (size_t)(N + 4) * 4;
    int*   rowend = (int*)w;              w += (size_t)(N + 4) * 4;
    float* dis    = (float*)w;            w += (size_t)N * 4;
    float* d2     = (float*)w;            w += (size_t)N * 4;
    float* inv    = (float*)w;            w += (size_t)N * 4;
    int*   tmp    = (int*)w;              w += (size_t)NBUCK_MAX * CAPB * 4;
    int*   psrc   = (int*)w;              w += (size_t)NBUCK_MAX * CAPB * 4;
    uint4* u0     = (uint4*)w;            w += (size_t)64 * N;   // 32 bf16 = 64B rows
    uint4* u1     = (uint4*)w;            w += (size_t)64 * N;
    uint4* u2     = (uint4*)w;            w += (size_t)64 * N;
    uint4* u3     = (uint4*)w;            w += (size_t)64 * N;
    uint4* hb     = (uint4*)w;            w += (size_t)32 * N;   // 16 bf16 = 32B rows
    uint4* uh     = (uint4*)w;            w += (size_t)32 * N;
    uint4* us1    = (uint4*)w;            w += (size_t)32 * N;
    uint4* us2    = (uint4*)w;            w += (size_t)32 * N;
    uint4* us3    = (uint4*)w;            w += (size_t)32 * N;

    int gN   = (N + BLK - 1) / BLK;
    int gN2  = (N * 2 + BLK - 1) / BLK;   // combine1: 2 threads/node
    int gU32 = (N * 4 + BLK - 1) / BLK;   // 4 lanes/node
    int gU16 = (N * 2 + BLK - 1) / BLK;   // 2 lanes/node
    int gCH  = (E + CHUNK - 1) / CHUNK;

    // ---- CSR build (2 kernels; u0 conversion fused into bucket_place) ----
    hipMemsetAsync(bfill, 0, NBUCK_MAX * sizeof(int), stream);
    binned_scatter_kernel<<<gCH, BLK, 0, stream>>>(src, dst, bfill, tmp, E, nbuck);
    bucket_place_kernel<<<nbuck, BLKP, 0, stream>>>(bfill, tmp, psrc, rowbeg, rowend,
                                                    dis, d2, inv, x, u0, N);

    // ---- layer 1 (F=32, bf16 U-tables, 64B rows) ----
    prop_u_kernel<4, false><<<gU32, BLK, 0, stream>>>(rowbeg, rowend, psrc, d2, u0, nullptr, u1, 1.0f, N);
    prop_u_kernel<4, true ><<<gU32, BLK, 0, stream>>>(rowbeg, rowend, psrc, d2, u1, u0,      u2, 2.0f, N);
    prop_u_kernel<4, true ><<<gU32, BLK, 0, stream>>>(rowbeg, rowend, psrc, d2, u2, u1,      u3, 2.0f, N);
    combine1_kernel<<<gN2, BLK, 0, stream>>>(x, u1, u2, u3, inv, dis, W1, b1, hb, uh, N);

    // ---- layer 2 (F=16, bf16 U-tables, 32B rows) ----
    prop_u_kernel<2, false><<<gU16, BLK, 0, stream>>>(rowbeg, rowend, psrc, d2, uh,  nullptr, us1, 1.0f, N);
    prop_u_kernel<2, true ><<<gU16, BLK, 0, stream>>>(rowbeg, rowend, psrc, d2, us1, uh,      us2, 2.0f, N);
    prop_u_kernel<2, true ><<<gU16, BLK, 0, stream>>>(rowbeg, rowend, psrc, d2, us2, us1,     us3, 2.0f, N);
    combine2_kernel<<<gN, BLK, 0, stream>>>(hb, us1, us2, us3, inv, W2, b2, out, N);
}